// Round 10
// baseline (456.515 us; speedup 1.0000x reference)
//
#include <hip/hip_runtime.h>

// N=1024, D=16, H=32, 3H=96.  All tensors fp32 (per reference dtypes).
//
// SESSION LEDGER (what is PROVEN on this harness):
//   R4/R7: passed, 439.2/439.5us, gru 203.5us, absmax 0.001953125.
//   R9:    passed, 448.3us total (noisy residual), gru 196.5us, absmax
//          EXACTLY 0.001953125 -- dbuf pipeline + HARDENED half_swap.
//   R3/R6/R8 failures: ROOT-CAUSED to half_swap's two "+v" operands both
//          init'd from one value; coalescer could merge them into ONE
//          physical reg (context-dependent) => permlane_swap v,v == r/z
//          exchange.  Fixed by earlyclobber form below.  R6's pieces
//          {8x2 tree, readlane reorder, hm1 tail} are exonerated (R10
//          re-tests them on the fixed base).
//   RTZ on recurrent h: still quarantined (R5, plausible bias-integration);
//          h pack stays RNE.
//   Non-gru residual (total - 2*gru) is launch/clock noise, 33-55us across
//          identical proj/clf code; judge rounds by gru counters.

typedef _Float16 hv2 __attribute__((ext_vector_type(2)));
typedef _Float16 hv8 __attribute__((ext_vector_type(8)));
typedef float    fv4 __attribute__((ext_vector_type(4)));
typedef unsigned uv4 __attribute__((ext_vector_type(4)));

// pack two fp32 -> f16 pair bits (v_cvt_pkrtz_f16_f32).
// RTZ is safe for STATIC WEIGHTS ONLY (R5 lesson: recurrent h must be RNE).
__device__ __forceinline__ unsigned pkh(float a, float b) {
    auto t = __builtin_amdgcn_cvt_pkrtz(a, b);
    return __builtin_bit_cast(unsigned, t);
}
__device__ __forceinline__ fv4 splat4(float v) { return fv4{v, v, v, v}; }
// fast reciprocal: v_rcp_f32 (~1 ulp; verified accuracy-neutral)
#if __has_builtin(__builtin_amdgcn_rcpf)
__device__ __forceinline__ float frcp(float x) { return __builtin_amdgcn_rcpf(x); }
#else
__device__ __forceinline__ float frcp(float x) { return 1.f / x; }
#endif
// bare v_exp_f32 (2^x); all weights/biases prescaled by log2e factors
#if __has_builtin(__builtin_amdgcn_exp2f)
__device__ __forceinline__ float fexp2(float x) { return __builtin_amdgcn_exp2f(x); }
#else
__device__ __forceinline__ float fexp2(float x) { return exp2f(x); }
#endif
// dot2: c += a.x*b.x + a.y*b.y   (f16 inputs, f32 accumulate)
#if __has_builtin(__builtin_amdgcn_fdot2)
__device__ __forceinline__ float d2(unsigned a, unsigned b, float c) {
    return __builtin_amdgcn_fdot2(__builtin_bit_cast(hv2, a),
                                  __builtin_bit_cast(hv2, b), c, false);
}
#else
__device__ __forceinline__ float d2(unsigned a, unsigned b, float c) {
    hv2 x = __builtin_bit_cast(hv2, a), y = __builtin_bit_cast(hv2, b);
    return fmaf((float)x.x, (float)y.x, fmaf((float)x.y, (float)y.y, c));
}
#endif
// lane 2k reads lane 2k+1 (quad_perm [1,0,3,2] = 0xB1); all lanes active
__device__ __forceinline__ float dpp_xor1(float x) {
    int r = __builtin_amdgcn_update_dpp(0, __builtin_bit_cast(int, x),
                                        0xB1, 0xF, 0xF, true);
    return __builtin_bit_cast(float, r);
}
// HARDENED half_swap (R9-proven).  v_permlane32_swap_b32 d, s requires d and
// s in DISTINCT physical registers; s is an earlyclobber output filled by an
// opaque in-asm copy, so the coalescer cannot alias it with d.
//   lo_all := x's lanes 0..31 replicated to both halves
//   hi_all := x's lanes 32..63 replicated to both halves
__device__ __forceinline__ void half_swap(float x, float& lo_all, float& hi_all) {
    float d = x, s;
    asm("v_mov_b32 %1, %0\n\t"
        "v_permlane32_swap_b32 %0, %1"
        : "+v"(d), "=&v"(s));
    lo_all = d;
    hi_all = s;
}

// log2(e) scale constants (folded into weights/biases at setup)
#define SRZ (-1.44269504088896341f)   /* r/z: exp(-g) = exp2(SRZ*g) */
#define SN  ( 2.88539008177792682f)   /* n:   exp(2y) = exp2(SN*y)  */

// ---------------------------------------------------------------------------
// K1/K3: pairwise rank-split (unchanged, proven).
// ---------------------------------------------------------------------------
__global__ void proj1_kernel(const float* __restrict__ x, const float* __restrict__ w,
                             const float* __restrict__ bias,
                             float* __restrict__ A, float* __restrict__ B) {
    int idx = blockIdx.x * 256 + threadIdx.x;      // 0..32767
    int i = idx >> 5, h = idx & 31;
    float sa = bias[h];
    float sb = 0.f;
#pragma unroll
    for (int d = 0; d < 16; ++d) {
        float xv = x[i * 16 + d];
        float wa = w[h * 32 + d];
        float wb = w[h * 32 + 16 + d];
        sa += (wa - wb) * xv;
        sb += wb * xv;
    }
    A[i * 32 + h] = sa;
    B[i * 32 + h] = sb;
}

__global__ void proj2_kernel(const float* __restrict__ h1, const float* __restrict__ w,
                             const float* __restrict__ bias,
                             float* __restrict__ A, float* __restrict__ B) {
    int idx = blockIdx.x * 256 + threadIdx.x;      // 0..32767
    int i = idx >> 5, h = idx & 31;
    float sa = bias[h];
    float sb = 0.f;
#pragma unroll
    for (int k = 0; k < 32; ++k) {
        float hv = h1[i * 32 + k];
        float wa = w[h * 64 + k];
        float wb = w[h * 64 + 32 + k];
        sa += (wa - wb) * hv;
        sb += wb * hv;
    }
    A[i * 32 + h] = sa;
    B[i * 32 + h] = sb;
}

// ---- chunk compute (R4 body, buffer-parameterized).  Consumes blo/bhi
//      (rows of the chunk being computed), loads rows for timestep TLOAD. ----
#define CHUNK(BUF, TLOAD) do {                                                \
    uv4 xb_;                                                                  \
    _Pragma("unroll")                                                         \
    for (int r_ = 0; r_ < 4; ++r_)                                            \
        xb_[r_] = pkh(fmaxf(alo[r_] + blo[r_], 0.f),                          \
                      fmaxf(ahi[r_] + bhi[r_], 0.f));                         \
    hv8 xf_ = __builtin_bit_cast(hv8, xb_);                                   \
    blo = B4[((TLOAD) + m0) * 8 + q];                                         \
    bhi = B4[((TLOAD) + m0) * 8 + 4 + q];                                     \
    _Pragma("unroll")                                                         \
    for (int T_ = 0; T_ < 6; ++T_) {                                          \
        fv4 D_ = __builtin_amdgcn_mfma_f32_16x16x32_f16(xf_, WI[T_],          \
                                                splat4(bi[T_]), 0, 0, 0);     \
        fv4 e_;                                                               \
        if (T_ < 4) {                                                         \
            _Pragma("unroll")                                                 \
            for (int r_ = 0; r_ < 4; ++r_) e_[r_] = fexp2(D_[r_]);            \
        } else {                                                              \
            e_ = D_;                                                          \
        }                                                                     \
        *(fv4*)&xg[BUF][T_][m0][4 * q] = e_;                                  \
    }                                                                         \
} while (0)

// ---- 16 serial GRU steps reading buffer BUF.
//      R10: + 8x2-deep own-gate dot w/ 3-level tree, chain-head-first
//      readlanes, hm1 tail (exonerated R6 pieces on the hardened base). ----
#define SERIAL16(BUF) do {                                                    \
    fv4 Ex = *(const fv4*)&xg[BUF][TX][mc][0];                                \
    fv4 Xn = *(const fv4*)&xg[BUF][4 + Tq][mc][0];                            \
    _Pragma("unroll")                                                         \
    for (int g_ = 0; g_ < 4; ++g_) {                                          \
        const fv4 cEx = Ex, cXn = Xn;                                         \
        int ng_ = (g_ + 1) & 3;                                               \
        Ex = *(const fv4*)&xg[BUF][TX][mc][4 * ng_];                          \
        Xn = *(const fv4*)&xg[BUF][4 + Tq][mc][4 * ng_];                      \
        _Pragma("unroll")                                                     \
        for (int j_ = 0; j_ < 4; ++j_) {                                      \
            const float ex = cEx[j_];                                         \
            const float xn = cXn[j_];                                         \
            float hnb = dpp_xor1(h_l);                                        \
            hv2 hp;                                                           \
            hp.x = (_Float16)h_l;   /* RNE (required; R5 lesson) */           \
            hp.y = (_Float16)hnb;                                             \
            unsigned pk = __builtin_bit_cast(unsigned, hp);                   \
            unsigned Hs[16];                                                  \
            _Pragma("unroll")                                                 \
            for (int k_ = 0; k_ < 8; ++k_)  /* even = chain heads first */    \
                Hs[2 * k_] = (unsigned)__builtin_amdgcn_readlane((int)pk, 4 * k_);\
            _Pragma("unroll")                                                 \
            for (int k_ = 0; k_ < 8; ++k_)  /* odd pairs */                   \
                Hs[2 * k_ + 1] = (unsigned)__builtin_amdgcn_readlane((int)pk, 4 * k_ + 2);\
            float p0 = brz, p1 = 0.f, p2 = 0.f, p3 = 0.f;                     \
            float p4 = 0.f, p5 = 0.f, p6 = 0.f, p7 = 0.f;                     \
            p0 = d2(grz[0],  Hs[0],  p0);  p0 = d2(grz[1],  Hs[1],  p0);      \
            p1 = d2(grz[2],  Hs[2],  p1);  p1 = d2(grz[3],  Hs[3],  p1);      \
            p2 = d2(grz[4],  Hs[4],  p2);  p2 = d2(grz[5],  Hs[5],  p2);      \
            p3 = d2(grz[6],  Hs[6],  p3);  p3 = d2(grz[7],  Hs[7],  p3);      \
            p4 = d2(grz[8],  Hs[8],  p4);  p4 = d2(grz[9],  Hs[9],  p4);      \
            p5 = d2(grz[10], Hs[10], p5);  p5 = d2(grz[11], Hs[11], p5);      \
            p6 = d2(grz[12], Hs[12], p6);  p6 = d2(grz[13], Hs[13], p6);      \
            p7 = d2(grz[14], Hs[14], p7);  p7 = d2(grz[15], Hs[15], p7);      \
            float gfull = ((p0 + p1) + (p2 + p3)) + ((p4 + p5) + (p6 + p7));  \
            float eh  = fexp2(gfull);                                         \
            float sig = frcp(fmaf(ex, eh, 1.f));                              \
            float r, z;                                                       \
            half_swap(sig, r, z);                                             \
            float s   = fmaf(z, hm1, 1.f);   /* z*h + (1-z) */                \
            float t2  = fmaf(2.f, z, -2.f);  /* -2*(1-z)    */                \
            float na = bhn2, nb2 = 0.f, nc2 = 0.f, nd2 = 0.f;                 \
            _Pragma("unroll")                                                 \
            for (int k_ = 0; k_ < 4; ++k_) {                                  \
                na  = d2(wn2[k_],      Hs[k_],      na);                      \
                nb2 = d2(wn2[k_ + 4],  Hs[k_ + 4],  nb2);                     \
                nc2 = d2(wn2[k_ + 8],  Hs[k_ + 8],  nc2);                     \
                nd2 = d2(wn2[k_ + 12], Hs[k_ + 12], nd2);                     \
            }                                                                 \
            float hn2 = (na + nb2) + (nc2 + nd2);                             \
            float y  = fmaf(r, hn2, xn);                                      \
            float E  = fexp2(y);                                              \
            float rE = frcp(E + 1.f);                                         \
            h_l = fmaf(t2, rE, s);                                            \
            hm1 = h_l - 1.f;                 /* off-path, for next step */    \
        }                                                                     \
    }                                                                         \
} while (0)

// ---------------------------------------------------------------------------
// GRU, one chain per wave, 1024 blocks (1 wave on every SIMD).
//   R9-proven structure: double-buffered xg; chunk k+1 ISSUED before
//   serial16 of chunk k (global-load/MFMA/exp drain hides under serial);
//   every chunk-write separated from its serial-read by full __syncthreads.
// ---------------------------------------------------------------------------
__global__ __launch_bounds__(64, 1) void gru_kernel(
    const float* __restrict__ A, const float* __restrict__ B,
    const float* __restrict__ wih, const float* __restrict__ whh,
    const float* __restrict__ bih, const float* __restrict__ bhh,
    float* __restrict__ h_out,
    const float* __restrict__ clfw, const float* __restrict__ clfb,
    float* __restrict__ out3) {
    const int l = threadIdx.x;         // 0..63
    const int q = l >> 4;              // k-slot group (chunk MFMA)
    const int m0 = l & 15;             // MFMA col
    const int m = l & 31;              // gate/hidden index (halves mirrored)
    const int c = blockIdx.x;          // chain

    __shared__ float xg[2][6][16][20]; // double buffer [tile][col][t] (+pad 4)

    // ---- chunk-phase weights: Wih B-frags, prescaled per-tile ----
    hv8 WI[6];
#pragma unroll
    for (int T = 0; T < 6; ++T) {
        const float sc = (T < 4) ? SRZ : SN;
        int g = 16 * T + m0;
        uv4 wi;
#pragma unroll
        for (int r = 0; r < 4; ++r) {
            int lo = 4 * q + r;
            wi[r] = pkh(wih[g * 32 + lo] * sc, wih[g * 32 + lo + 16] * sc);
        }
        WI[T] = __builtin_bit_cast(hv8, wi);
    }
    float bi[6];
#pragma unroll
    for (int T = 0; T < 6; ++T) bi[T] = bih[16 * T + m0] * ((T < 4) ? SRZ : SN);

    // ---- serial-phase weights, prescaled ----
    // lanes<32: whh r-rows (m);  lanes>=32: whh z-rows (32+m).  n-rows mirrored.
    const int grow = (l < 32) ? m : (32 + m);
    unsigned grz[16], wn2[16];
#pragma unroll
    for (int k = 0; k < 16; ++k) {
        grz[k] = pkh(whh[grow * 32 + 2 * k] * SRZ,     whh[grow * 32 + 2 * k + 1] * SRZ);
        wn2[k] = pkh(whh[(64 + m) * 32 + 2 * k] * SN,  whh[(64 + m) * 32 + 2 * k + 1] * SN);
    }
    const float brz  = bhh[grow] * SRZ;
    const float bhn2 = bhh[64 + m] * SN;

    const fv4* A4 = (const fv4*)A;     // [chain*8 + slot]
    const fv4* B4 = (const fv4*)B;     // [t*8 + slot]
    const fv4 alo = A4[c * 8 + q];
    const fv4 ahi = A4[c * 8 + 4 + q];

    // chunk staging: this lane supplies timestep (chunk_base + m0)
    fv4 blo = B4[m0 * 8 + q], bhi = B4[m0 * 8 + 4 + q];   // chunk 0 rows

    float h_l = 0.f;                   // h_m (mirrored in both halves)
    float hm1 = -1.f;                  // h_l - 1 (maintained off-path)

    const int Tq = m >> 4;             // 0 for m<16, 1 for m>=16
    const int mc = m & 15;
    const int TX = (l < 32) ? Tq : (2 + Tq);  // own-gate x-side exp tile

    // ---- pipelined main loop: 64 chunks of 16 steps ----
    CHUNK(0, 16);                      // chunk 0 -> buf0; loads rows t=16
    __syncthreads();
    for (int c0 = 0; c0 < 992; c0 += 32) {
        CHUNK(1, (c0 + 32) & 1023);    // chunk (c0/16)+1 -> buf1; loads c0+32
        SERIAL16(0);                   // steps c0..c0+15 (buf0, barrier'd)
        __syncthreads();               // drains buf1 writes (hidden under serial)
        CHUNK(0, (c0 + 48) & 1023);    // chunk (c0/16)+2 -> buf0; loads c0+48
        SERIAL16(1);                   // steps c0+16..c0+31
        __syncthreads();               // drains buf0 writes
    }
    // after loop: serial done through step 991; buf0 holds chunk 62
    CHUNK(1, 0);                       // chunk 63 -> buf1 (dummy row load t=0)
    SERIAL16(0);                       // steps 992..1007
    __syncthreads();                   // drains chunk-63 writes
    SERIAL16(1);                       // steps 1008..1023

    if (clfw) {
        // ---- fused classifier (layer 2): bit-identical fp32 math ----
        float* hs = (float*)xg;
        if (l < 32) hs[m] = h_l;
        __syncthreads();
        if (l < 3) {
            float s = clfb[l];
#pragma unroll
            for (int k = 0; k < 32; ++k) s += clfw[l * 32 + k] * hs[k];
            out3[c * 3 + l] = s;
        }
    } else {
        if (l < 32) h_out[c * 32 + m] = h_l;
    }
}

extern "C" void kernel_launch(void* const* d_in, const int* in_sizes, int n_in,
                              void* d_out, int out_size, void* d_ws, size_t ws_size,
                              hipStream_t stream) {
    const float* x       = (const float*)d_in[0];
    const float* p1w     = (const float*)d_in[1];
    const float* p1b     = (const float*)d_in[2];
    const float* g1_wih  = (const float*)d_in[3];
    const float* g1_whh  = (const float*)d_in[4];
    const float* g1_bih  = (const float*)d_in[5];
    const float* g1_bhh  = (const float*)d_in[6];
    const float* p2w     = (const float*)d_in[7];
    const float* p2b     = (const float*)d_in[8];
    const float* g2_wih  = (const float*)d_in[9];
    const float* g2_whh  = (const float*)d_in[10];
    const float* g2_bih  = (const float*)d_in[11];
    const float* g2_bhh  = (const float*)d_in[12];
    const float* clfw    = (const float*)d_in[13];
    const float* clfb    = (const float*)d_in[14];

    // Workspace layout (reused across stages; 3 x 32768 floats = 384 KB):
    float* ws = (float*)d_ws;
    float* A  = ws;              // A1 then A2
    float* Bt = ws + 32768;      // B1 then B2
    float* h  = ws + 65536;      // h1

    proj1_kernel<<<128, 256, 0, stream>>>(x, p1w, p1b, A, Bt);
    gru_kernel<<<1024, 64, 0, stream>>>(A, Bt, g1_wih, g1_whh, g1_bih, g1_bhh, h,
                                        nullptr, nullptr, nullptr);
    proj2_kernel<<<128, 256, 0, stream>>>(h, p2w, p2b, A, Bt);
    gru_kernel<<<1024, 64, 0, stream>>>(A, Bt, g2_wih, g2_whh, g2_bih, g2_bhh, h,
                                        clfw, clfb, (float*)d_out);
}

// Round 11
// 446.098 us; speedup vs baseline: 1.0234x; 1.0234x over previous
//
#include <hip/hip_runtime.h>

// N=1024, D=16, H=32, 3H=96.  All tensors fp32 (per reference dtypes).
//
// SESSION LEDGER (what is PROVEN on this harness):
//   R4/R7: passed, 439.2/439.5us, gru 203.5us, absmax 0.001953125.
//   R9:    passed, gru 196.5us, absmax EXACTLY 0.001953125
//          (dbuf pipeline + HARDENED half_swap).  <-- BEST VERIFIED; this file.
//   R10 (R9 + 8x2 tree + readlane reorder + hm1 tail): passed, absmax exact,
//          but gru 207.2us (+5.4%) -- numerically sound, REGRESSED perf.
//          Lesson: R9's serial body is a local optimum; no idle issue slots.
//   R3/R6/R8 failures: ROOT-CAUSED to half_swap's two "+v" operands both
//          init'd from one value; coalescer could merge them into ONE
//          physical reg => permlane_swap v,v == r/z exchange.  Fixed below
//          (earlyclobber).  Keep the hardened form forever.
//   RTZ on recurrent h: quarantined (R5, bias integrates through recursion);
//          h pack stays RNE.
//   Non-gru residual (total - 2*gru) is launch/clock noise, 33-55us across
//          identical proj/clf code; judge rounds by gru counters.

typedef _Float16 hv2 __attribute__((ext_vector_type(2)));
typedef _Float16 hv8 __attribute__((ext_vector_type(8)));
typedef float    fv4 __attribute__((ext_vector_type(4)));
typedef unsigned uv4 __attribute__((ext_vector_type(4)));

// pack two fp32 -> f16 pair bits (v_cvt_pkrtz_f16_f32).
// RTZ is safe for STATIC WEIGHTS ONLY (R5 lesson: recurrent h must be RNE).
__device__ __forceinline__ unsigned pkh(float a, float b) {
    auto t = __builtin_amdgcn_cvt_pkrtz(a, b);
    return __builtin_bit_cast(unsigned, t);
}
__device__ __forceinline__ fv4 splat4(float v) { return fv4{v, v, v, v}; }
// fast reciprocal: v_rcp_f32 (~1 ulp; verified accuracy-neutral)
#if __has_builtin(__builtin_amdgcn_rcpf)
__device__ __forceinline__ float frcp(float x) { return __builtin_amdgcn_rcpf(x); }
#else
__device__ __forceinline__ float frcp(float x) { return 1.f / x; }
#endif
// bare v_exp_f32 (2^x); all weights/biases prescaled by log2e factors
#if __has_builtin(__builtin_amdgcn_exp2f)
__device__ __forceinline__ float fexp2(float x) { return __builtin_amdgcn_exp2f(x); }
#else
__device__ __forceinline__ float fexp2(float x) { return exp2f(x); }
#endif
// dot2: c += a.x*b.x + a.y*b.y   (f16 inputs, f32 accumulate)
#if __has_builtin(__builtin_amdgcn_fdot2)
__device__ __forceinline__ float d2(unsigned a, unsigned b, float c) {
    return __builtin_amdgcn_fdot2(__builtin_bit_cast(hv2, a),
                                  __builtin_bit_cast(hv2, b), c, false);
}
#else
__device__ __forceinline__ float d2(unsigned a, unsigned b, float c) {
    hv2 x = __builtin_bit_cast(hv2, a), y = __builtin_bit_cast(hv2, b);
    return fmaf((float)x.x, (float)y.x, fmaf((float)x.y, (float)y.y, c));
}
#endif
// lane 2k reads lane 2k+1 (quad_perm [1,0,3,2] = 0xB1); all lanes active
__device__ __forceinline__ float dpp_xor1(float x) {
    int r = __builtin_amdgcn_update_dpp(0, __builtin_bit_cast(int, x),
                                        0xB1, 0xF, 0xF, true);
    return __builtin_bit_cast(float, r);
}
// HARDENED half_swap (R9-proven).  v_permlane32_swap_b32 d, s requires d and
// s in DISTINCT physical registers; s is an earlyclobber output filled by an
// opaque in-asm copy, so the coalescer cannot alias it with d.
//   lo_all := x's lanes 0..31 replicated to both halves
//   hi_all := x's lanes 32..63 replicated to both halves
__device__ __forceinline__ void half_swap(float x, float& lo_all, float& hi_all) {
    float d = x, s;
    asm("v_mov_b32 %1, %0\n\t"
        "v_permlane32_swap_b32 %0, %1"
        : "+v"(d), "=&v"(s));
    lo_all = d;
    hi_all = s;
}

// log2(e) scale constants (folded into weights/biases at setup)
#define SRZ (-1.44269504088896341f)   /* r/z: exp(-g) = exp2(SRZ*g) */
#define SN  ( 2.88539008177792682f)   /* n:   exp(2y) = exp2(SN*y)  */

// ---------------------------------------------------------------------------
// K1/K3: pairwise rank-split (unchanged, proven).
// ---------------------------------------------------------------------------
__global__ void proj1_kernel(const float* __restrict__ x, const float* __restrict__ w,
                             const float* __restrict__ bias,
                             float* __restrict__ A, float* __restrict__ B) {
    int idx = blockIdx.x * 256 + threadIdx.x;      // 0..32767
    int i = idx >> 5, h = idx & 31;
    float sa = bias[h];
    float sb = 0.f;
#pragma unroll
    for (int d = 0; d < 16; ++d) {
        float xv = x[i * 16 + d];
        float wa = w[h * 32 + d];
        float wb = w[h * 32 + 16 + d];
        sa += (wa - wb) * xv;
        sb += wb * xv;
    }
    A[i * 32 + h] = sa;
    B[i * 32 + h] = sb;
}

__global__ void proj2_kernel(const float* __restrict__ h1, const float* __restrict__ w,
                             const float* __restrict__ bias,
                             float* __restrict__ A, float* __restrict__ B) {
    int idx = blockIdx.x * 256 + threadIdx.x;      // 0..32767
    int i = idx >> 5, h = idx & 31;
    float sa = bias[h];
    float sb = 0.f;
#pragma unroll
    for (int k = 0; k < 32; ++k) {
        float hv = h1[i * 32 + k];
        float wa = w[h * 64 + k];
        float wb = w[h * 64 + 32 + k];
        sa += (wa - wb) * hv;
        sb += wb * hv;
    }
    A[i * 32 + h] = sa;
    B[i * 32 + h] = sb;
}

// ---- chunk compute (R4 body, buffer-parameterized).  Consumes blo/bhi
//      (rows of the chunk being computed), loads rows for timestep TLOAD. ----
#define CHUNK(BUF, TLOAD) do {                                                \
    uv4 xb_;                                                                  \
    _Pragma("unroll")                                                         \
    for (int r_ = 0; r_ < 4; ++r_)                                            \
        xb_[r_] = pkh(fmaxf(alo[r_] + blo[r_], 0.f),                          \
                      fmaxf(ahi[r_] + bhi[r_], 0.f));                         \
    hv8 xf_ = __builtin_bit_cast(hv8, xb_);                                   \
    blo = B4[((TLOAD) + m0) * 8 + q];                                         \
    bhi = B4[((TLOAD) + m0) * 8 + 4 + q];                                     \
    _Pragma("unroll")                                                         \
    for (int T_ = 0; T_ < 6; ++T_) {                                          \
        fv4 D_ = __builtin_amdgcn_mfma_f32_16x16x32_f16(xf_, WI[T_],          \
                                                splat4(bi[T_]), 0, 0, 0);     \
        fv4 e_;                                                               \
        if (T_ < 4) {                                                         \
            _Pragma("unroll")                                                 \
            for (int r_ = 0; r_ < 4; ++r_) e_[r_] = fexp2(D_[r_]);            \
        } else {                                                              \
            e_ = D_;                                                          \
        }                                                                     \
        *(fv4*)&xg[BUF][T_][m0][4 * q] = e_;                                  \
    }                                                                         \
} while (0)

// ---- 16 serial GRU steps reading buffer BUF (R4 body, verbatim).
//      R10 lesson: do NOT perturb this body (8x2 tree / readlane reorder /
//      hm1 tail all passed correctness but cost +5.4% -- no idle slots). ----
#define SERIAL16(BUF) do {                                                    \
    fv4 Ex = *(const fv4*)&xg[BUF][TX][mc][0];                                \
    fv4 Xn = *(const fv4*)&xg[BUF][4 + Tq][mc][0];                            \
    _Pragma("unroll")                                                         \
    for (int g_ = 0; g_ < 4; ++g_) {                                          \
        const fv4 cEx = Ex, cXn = Xn;                                         \
        int ng_ = (g_ + 1) & 3;                                               \
        Ex = *(const fv4*)&xg[BUF][TX][mc][4 * ng_];                          \
        Xn = *(const fv4*)&xg[BUF][4 + Tq][mc][4 * ng_];                      \
        _Pragma("unroll")                                                     \
        for (int j_ = 0; j_ < 4; ++j_) {                                      \
            const float ex = cEx[j_];                                         \
            const float xn = cXn[j_];                                         \
            float hnb = dpp_xor1(h_l);                                        \
            hv2 hp;                                                           \
            hp.x = (_Float16)h_l;   /* RNE (required; R5 lesson) */           \
            hp.y = (_Float16)hnb;                                             \
            unsigned pk = __builtin_bit_cast(unsigned, hp);                   \
            unsigned Hs[16];                                                  \
            _Pragma("unroll")                                                 \
            for (int k_ = 0; k_ < 16; ++k_)                                   \
                Hs[k_] = (unsigned)__builtin_amdgcn_readlane((int)pk, 2 * k_);\
            float ga = brz, gb = 0.f, gc = 0.f, gd = 0.f;                     \
            _Pragma("unroll")                                                 \
            for (int k_ = 0; k_ < 4; ++k_) {                                  \
                ga = d2(grz[k_],      Hs[k_],      ga);                       \
                gb = d2(grz[k_ + 4],  Hs[k_ + 4],  gb);                       \
                gc = d2(grz[k_ + 8],  Hs[k_ + 8],  gc);                       \
                gd = d2(grz[k_ + 12], Hs[k_ + 12], gd);                       \
            }                                                                 \
            float gfull = (ga + gb) + (gc + gd);                              \
            float eh  = fexp2(gfull);                                         \
            float sig = frcp(fmaf(ex, eh, 1.f));                              \
            float r, z;                                                       \
            half_swap(sig, r, z);                                             \
            float omz = 1.f - z;                                              \
            float s   = fmaf(z, h_l, omz);                                    \
            float t2  = -2.f * omz;                                           \
            float na = bhn2, nb2 = 0.f, nc2 = 0.f, nd2 = 0.f;                 \
            _Pragma("unroll")                                                 \
            for (int k_ = 0; k_ < 4; ++k_) {                                  \
                na  = d2(wn2[k_],      Hs[k_],      na);                      \
                nb2 = d2(wn2[k_ + 4],  Hs[k_ + 4],  nb2);                     \
                nc2 = d2(wn2[k_ + 8],  Hs[k_ + 8],  nc2);                     \
                nd2 = d2(wn2[k_ + 12], Hs[k_ + 12], nd2);                     \
            }                                                                 \
            float hn2 = (na + nb2) + (nc2 + nd2);                             \
            float y  = fmaf(r, hn2, xn);                                      \
            float E  = fexp2(y);                                              \
            float rE = frcp(E + 1.f);                                         \
            h_l = fmaf(t2, rE, s);                                            \
        }                                                                     \
    }                                                                         \
} while (0)

// ---------------------------------------------------------------------------
// GRU, one chain per wave, 1024 blocks (1 wave on every SIMD).
//   R9-proven structure: double-buffered xg; chunk k+1 ISSUED before
//   serial16 of chunk k (global-load/MFMA/exp drain hides under serial);
//   every chunk-write separated from its serial-read by full __syncthreads.
// ---------------------------------------------------------------------------
__global__ __launch_bounds__(64, 1) void gru_kernel(
    const float* __restrict__ A, const float* __restrict__ B,
    const float* __restrict__ wih, const float* __restrict__ whh,
    const float* __restrict__ bih, const float* __restrict__ bhh,
    float* __restrict__ h_out,
    const float* __restrict__ clfw, const float* __restrict__ clfb,
    float* __restrict__ out3) {
    const int l = threadIdx.x;         // 0..63
    const int q = l >> 4;              // k-slot group (chunk MFMA)
    const int m0 = l & 15;             // MFMA col
    const int m = l & 31;              // gate/hidden index (halves mirrored)
    const int c = blockIdx.x;          // chain

    __shared__ float xg[2][6][16][20]; // double buffer [tile][col][t] (+pad 4)

    // ---- chunk-phase weights: Wih B-frags, prescaled per-tile ----
    hv8 WI[6];
#pragma unroll
    for (int T = 0; T < 6; ++T) {
        const float sc = (T < 4) ? SRZ : SN;
        int g = 16 * T + m0;
        uv4 wi;
#pragma unroll
        for (int r = 0; r < 4; ++r) {
            int lo = 4 * q + r;
            wi[r] = pkh(wih[g * 32 + lo] * sc, wih[g * 32 + lo + 16] * sc);
        }
        WI[T] = __builtin_bit_cast(hv8, wi);
    }
    float bi[6];
#pragma unroll
    for (int T = 0; T < 6; ++T) bi[T] = bih[16 * T + m0] * ((T < 4) ? SRZ : SN);

    // ---- serial-phase weights, prescaled ----
    // lanes<32: whh r-rows (m);  lanes>=32: whh z-rows (32+m).  n-rows mirrored.
    const int grow = (l < 32) ? m : (32 + m);
    unsigned grz[16], wn2[16];
#pragma unroll
    for (int k = 0; k < 16; ++k) {
        grz[k] = pkh(whh[grow * 32 + 2 * k] * SRZ,     whh[grow * 32 + 2 * k + 1] * SRZ);
        wn2[k] = pkh(whh[(64 + m) * 32 + 2 * k] * SN,  whh[(64 + m) * 32 + 2 * k + 1] * SN);
    }
    const float brz  = bhh[grow] * SRZ;
    const float bhn2 = bhh[64 + m] * SN;

    const fv4* A4 = (const fv4*)A;     // [chain*8 + slot]
    const fv4* B4 = (const fv4*)B;     // [t*8 + slot]
    const fv4 alo = A4[c * 8 + q];
    const fv4 ahi = A4[c * 8 + 4 + q];

    // chunk staging: this lane supplies timestep (chunk_base + m0)
    fv4 blo = B4[m0 * 8 + q], bhi = B4[m0 * 8 + 4 + q];   // chunk 0 rows

    float h_l = 0.f;                   // h_m (mirrored in both halves)

    const int Tq = m >> 4;             // 0 for m<16, 1 for m>=16
    const int mc = m & 15;
    const int TX = (l < 32) ? Tq : (2 + Tq);  // own-gate x-side exp tile

    // ---- pipelined main loop: 64 chunks of 16 steps ----
    CHUNK(0, 16);                      // chunk 0 -> buf0; loads rows t=16
    __syncthreads();
    for (int c0 = 0; c0 < 992; c0 += 32) {
        CHUNK(1, (c0 + 32) & 1023);    // chunk (c0/16)+1 -> buf1; loads c0+32
        SERIAL16(0);                   // steps c0..c0+15 (buf0, barrier'd)
        __syncthreads();               // drains buf1 writes (hidden under serial)
        CHUNK(0, (c0 + 48) & 1023);    // chunk (c0/16)+2 -> buf0; loads c0+48
        SERIAL16(1);                   // steps c0+16..c0+31
        __syncthreads();               // drains buf0 writes
    }
    // after loop: serial done through step 991; buf0 holds chunk 62
    CHUNK(1, 0);                       // chunk 63 -> buf1 (dummy row load t=0)
    SERIAL16(0);                       // steps 992..1007
    __syncthreads();                   // drains chunk-63 writes
    SERIAL16(1);                       // steps 1008..1023

    if (clfw) {
        // ---- fused classifier (layer 2): bit-identical fp32 math ----
        float* hs = (float*)xg;
        if (l < 32) hs[m] = h_l;
        __syncthreads();
        if (l < 3) {
            float s = clfb[l];
#pragma unroll
            for (int k = 0; k < 32; ++k) s += clfw[l * 32 + k] * hs[k];
            out3[c * 3 + l] = s;
        }
    } else {
        if (l < 32) h_out[c * 32 + m] = h_l;
    }
}

extern "C" void kernel_launch(void* const* d_in, const int* in_sizes, int n_in,
                              void* d_out, int out_size, void* d_ws, size_t ws_size,
                              hipStream_t stream) {
    const float* x       = (const float*)d_in[0];
    const float* p1w     = (const float*)d_in[1];
    const float* p1b     = (const float*)d_in[2];
    const float* g1_wih  = (const float*)d_in[3];
    const float* g1_whh  = (const float*)d_in[4];
    const float* g1_bih  = (const float*)d_in[5];
    const float* g1_bhh  = (const float*)d_in[6];
    const float* p2w     = (const float*)d_in[7];
    const float* p2b     = (const float*)d_in[8];
    const float* g2_wih  = (const float*)d_in[9];
    const float* g2_whh  = (const float*)d_in[10];
    const float* g2_bih  = (const float*)d_in[11];
    const float* g2_bhh  = (const float*)d_in[12];
    const float* clfw    = (const float*)d_in[13];
    const float* clfb    = (const float*)d_in[14];

    // Workspace layout (reused across stages; 3 x 32768 floats = 384 KB):
    float* ws = (float*)d_ws;
    float* A  = ws;              // A1 then A2
    float* Bt = ws + 32768;      // B1 then B2
    float* h  = ws + 65536;      // h1

    proj1_kernel<<<128, 256, 0, stream>>>(x, p1w, p1b, A, Bt);
    gru_kernel<<<1024, 64, 0, stream>>>(A, Bt, g1_wih, g1_whh, g1_bih, g1_bhh, h,
                                        nullptr, nullptr, nullptr);
    proj2_kernel<<<128, 256, 0, stream>>>(h, p2w, p2b, A, Bt);
    gru_kernel<<<1024, 64, 0, stream>>>(A, Bt, g2_wih, g2_whh, g2_bih, g2_bhh, h,
                                        clfw, clfb, (float*)d_out);
}